// Round 13
// baseline (187.541 us; speedup 1.0000x reference)
//
#include <hip/hip_runtime.h>
#include <stdint.h>

#define BN_EPS 1e-3f

constexpr int Bn = 32, H = 56, Wd = 56, C = 256;
constexpr int NSLOT = 240;          // 232 real slots + 8 pad (reads only)
typedef int v4i __attribute__((ext_vector_type(4)));
typedef int v16i __attribute__((ext_vector_type(16)));

__device__ __forceinline__ int imax(int a, int b) { return a > b ? a : b; }

// ---------------------------------------------------------------------------
// sign(x) -> i8 {+1,-1}
__global__ __launch_bounds__(256) void k_sign_x(const float* __restrict__ x,
                                                int8_t* __restrict__ xs, int n4) {
  int i = blockIdx.x * 256 + threadIdx.x;
  if (i >= n4) return;
  float4 v = ((const float4*)x)[i];
  char4 s;
  s.x = v.x >= 0.f ? 1 : -1;
  s.y = v.y >= 0.f ? 1 : -1;
  s.z = v.z >= 0.f ? 1 : -1;
  s.w = v.w >= 0.f ? 1 : -1;
  ((char4*)xs)[i] = s;
}

// ---------------------------------------------------------------------------
// Fragment-contiguous weights for mfma_i32_32x32x32_i8 B-operand:
// byte[((tap*8+ics)*8 + nsub)*1024 + l*16 + j] =
//   sign(w[tap][ic = ics*32 + (l>>5)*16 + j][oc = nsub*32 + (l&31)])
__global__ __launch_bounds__(256) void k_sign_wT3(const float* __restrict__ w,
                                                  uint32_t* __restrict__ wt) {
  int u = blockIdx.x * 256 + threadIdx.x;   // 0..147455
  int w4 = u & 3;
  int l = (u >> 2) & 63;
  int nsub = (u >> 8) & 7;
  int ics = (u >> 11) & 7;
  int tap = u >> 14;
  int oc = nsub * 32 + (l & 31);
  uint32_t pk = 0;
#pragma unroll
  for (int j = 0; j < 4; ++j) {
    int ic = ics * 32 + (l >> 5) * 16 + w4 * 4 + j;
    float v = w[((size_t)(tap * 256 + ic)) * 256 + oc];
    pk |= (v >= 0.f ? 0x01u : 0xFFu) << (8 * j);
  }
  wt[u] = pk;
}

// ---------------------------------------------------------------------------
// Implicit-GEMM conv, 3x3 SAME, mfma_i32_32x32x32_i8.
// Block = one row-pair: M=128 m-slots (112 real, permuted m = col*2+row so a
// 2x2 pool window = one lane's reg-quad), N=256. 4 waves = 2wm x 2wn; wave =
// 2 m-subtiles x 4 n-subtiles (acc = 8 x v16i = 128 AGPR). A in LDS (staged
// once, XOR-swizzled); af/bf double-buffered one K-step (32 ic) ahead.
template <int MODE>
__global__ __launch_bounds__(256, 2) void k_conv(
    const int8_t* __restrict__ src, const int8_t* __restrict__ wT3,
    const float* __restrict__ beta, const float* __restrict__ mean,
    const float* __restrict__ var,
    int8_t* __restrict__ hs, float* __restrict__ outp)
{
  const int t = threadIdx.x;
  const int rp = blockIdx.x;          // row pair 0..27
  const int b = blockIdx.y;
  const int rr0 = rp * 2;

  __shared__ __align__(16) int8_t As[NSLOT * 256];   // 61440 B

  // Stage A once: slot s = lr*58+colst (input rows rr0-1..rr0+2, halo cols),
  // 16B chunk c swizzled: byte = (s<<8) + ((c<<4) ^ ((s&7)<<4)).
  for (int i = t; i < 232 * 16; i += 256) {
    const int s = i >> 4, c = i & 15;
    const int lr = s / 58, colst = s - lr * 58;
    const int sr = rr0 + lr - 1, sc = colst - 1;
    uint4 v;
    v.x = v.y = v.z = v.w = 0u;
    if ((unsigned)sr < 56u && (unsigned)sc < 56u)
      v = *(const uint4*)(src + (((size_t)(b * 56 + sr)) * 56 + sc) * 256 + c * 16);
    *(uint4*)(As + (s << 8) + ((c << 4) ^ ((s & 7) << 4))) = v;
  }
  __syncthreads();

  const int lane = t & 63;
  const int wv = t >> 6;
  const int wm = wv >> 1, wn = wv & 1;
  const int col31 = lane & 31, kh = lane >> 5;
  const int kbyte = kh * 16;

  // A slot bases for this wave's 2 m-subtiles (m permuted: col*2+row)
  const int m0 = (wm * 2 + 0) * 32 + col31;
  const int m1 = (wm * 2 + 1) * 32 + col31;
  const int sb0 = (m0 & 1) * 58 + (m0 >> 1);
  const int sb1 = (m1 & 1) * 58 + (m1 >> 1);

  const int8_t* bpl = wT3 + (size_t)wn * 4096 + (size_t)lane * 16;

  v16i acc[2][4];
#pragma unroll
  for (int i = 0; i < 2; ++i)
#pragma unroll
    for (int j = 0; j < 4; ++j) acc[i][j] = (v16i)0;

#define LOADB(dst, st)                                                     \
  {                                                                        \
    const int8_t* p_ = bpl + (size_t)(st) * 8192;                          \
    dst[0] = *(const v4i*)(p_);                                            \
    dst[1] = *(const v4i*)(p_ + 1024);                                     \
    dst[2] = *(const v4i*)(p_ + 2048);                                     \
    dst[3] = *(const v4i*)(p_ + 3072);                                     \
  }

#define LOADA(dst, st)                                                     \
  {                                                                        \
    const int tap_ = (st) >> 3, ics_ = (st) & 7;                           \
    const int ky_ = tap_ / 3, kx_ = tap_ - 3 * ky_;                        \
    const int D_ = ky_ * 58 + kx_;                                         \
    const int ko_ = ics_ * 32 + kbyte;                                     \
    const int s0_ = sb0 + D_, s1_ = sb1 + D_;                              \
    dst[0] = *(const v4i*)(As + (s0_ << 8) + (ko_ ^ ((s0_ & 7) << 4)));    \
    dst[1] = *(const v4i*)(As + (s1_ << 8) + (ko_ ^ ((s1_ & 7) << 4)));    \
  }

#define MFMA8(af, bf)                                                      \
  __builtin_amdgcn_s_setprio(1);                                           \
  _Pragma("unroll") for (int ms = 0; ms < 2; ++ms)                         \
  _Pragma("unroll") for (int ns = 0; ns < 4; ++ns)                         \
      acc[ms][ns] = __builtin_amdgcn_mfma_i32_32x32x32_i8(                 \
          af[ms], bf[ns], acc[ms][ns], 0, 0, 0);                           \
  __builtin_amdgcn_s_setprio(0);

  v4i afA[2], afB[2], bfA[4], bfB[4];
  LOADA(afA, 0)
  LOADB(bfA, 0)

#pragma unroll 1
  for (int i = 0; i < 36; ++i) {
    const int s = 2 * i;
    const int s1 = s + 1;
    const int s2 = (s + 2 > 71) ? 71 : s + 2;
    LOADA(afB, s1)
    LOADB(bfB, s1)
    MFMA8(afA, bfA)
    LOADA(afA, s2)
    LOADB(bfA, s2)
    MFMA8(afB, bfB)
  }

#undef MFMA8
#undef LOADA
#undef LOADB

  // ---- epilogue ----
  // C/D 32x32 layout: oc_local = lane&31, m_local = (reg&3)+8*(reg>>2)+4*kh.
  const int rA = rp * 2;
  const int wbase = wn * 128;
  if (MODE == 0) {
    // BN1 + sign -> hs (NHWC i8)
#pragma unroll
    for (int ns = 0; ns < 4; ++ns) {
      const int oc = wbase + ns * 32 + col31;
      const float mu = mean[oc], rs = rsqrtf(var[oc] + BN_EPS), be = beta[oc];
#pragma unroll
      for (int msl = 0; msl < 2; ++msl) {
        const int msub = wm * 2 + msl;
#pragma unroll
        for (int reg = 0; reg < 16; ++reg) {
          const int m = msub * 32 + (reg & 3) + 8 * (reg >> 2) + 4 * kh;
          const int col = m >> 1, row = m & 1;
          if (col < 56) {
            const float bnv = ((float)acc[msl][ns][reg] - mu) * rs + be;
            hs[(((size_t)(b * 56 + rA + row)) * 56 + col) * 256 + oc] =
                bnv >= 0.f ? (int8_t)1 : (int8_t)-1;
          }
        }
      }
    }
  } else {
    // 2x2 maxpool (lane-local reg quads) + BN2 -> f32
#pragma unroll
    for (int ns = 0; ns < 4; ++ns) {
      const int oc = wbase + ns * 32 + col31;
      const float mu = mean[oc], rs = rsqrtf(var[oc] + BN_EPS), be = beta[oc];
#pragma unroll
      for (int msl = 0; msl < 2; ++msl) {
        const int msub = wm * 2 + msl;
#pragma unroll
        for (int g = 0; g < 4; ++g) {
          const int jj = msub * 8 + 2 * g + kh;   // pooled col
          if (jj < 28) {
            const int mx =
                imax(imax(acc[msl][ns][4 * g + 0], acc[msl][ns][4 * g + 1]),
                     imax(acc[msl][ns][4 * g + 2], acc[msl][ns][4 * g + 3]));
            outp[(((size_t)(b * 28 + rp)) * 28 + jj) * 256 + oc] =
                ((float)mx - mu) * rs + be;
          }
        }
      }
    }
  }
}

// ---------------------------------------------------------------------------
extern "C" void kernel_launch(void* const* d_in, const int* in_sizes, int n_in,
                              void* d_out, int out_size, void* d_ws, size_t ws_size,
                              hipStream_t stream) {
  const float* x     = (const float*)d_in[0];
  const float* w1    = (const float*)d_in[1];
  const float* beta1 = (const float*)d_in[2];
  const float* mean1 = (const float*)d_in[3];
  const float* var1  = (const float*)d_in[4];
  const float* w2    = (const float*)d_in[5];
  const float* beta2 = (const float*)d_in[6];
  const float* mean2 = (const float*)d_in[7];
  const float* var2  = (const float*)d_in[8];
  float* out = (float*)d_out;

  const size_t NPIX = (size_t)Bn * H * Wd * C;  // 25690112
  int8_t* xs  = (int8_t*)d_ws;
  int8_t* hs  = xs + NPIX;
  int8_t* w1t = hs + NPIX;
  int8_t* w2t = w1t + 589824;

  k_sign_x<<<dim3((int)(NPIX / 4 / 256)), 256, 0, stream>>>(x, xs, (int)(NPIX / 4));
  k_sign_wT3<<<dim3(576), 256, 0, stream>>>(w1, (uint32_t*)w1t);
  k_sign_wT3<<<dim3(576), 256, 0, stream>>>(w2, (uint32_t*)w2t);
  k_conv<0><<<dim3(28, Bn), 256, 0, stream>>>(xs, w1t, beta1, mean1, var1, hs, nullptr);
  k_conv<1><<<dim3(28, Bn), 256, 0, stream>>>(hs, w2t, beta2, mean2, var2, nullptr, out);
}

// Round 14
// 151.203 us; speedup vs baseline: 1.2403x; 1.2403x over previous
//
#include <hip/hip_runtime.h>
#include <stdint.h>

#define BN_EPS 1e-3f

constexpr int Bn = 32, H = 56, Wd = 56, C = 256;
constexpr int NSLOT = 232;          // 4 staged input rows * 58 cols (w/ halo)
typedef int v4i __attribute__((ext_vector_type(4)));

__device__ __forceinline__ int imax(int a, int b) { return a > b ? a : b; }

// ---------------------------------------------------------------------------
// sign(x) -> i8 {+1,-1}
__global__ __launch_bounds__(256) void k_sign_x(const float* __restrict__ x,
                                                int8_t* __restrict__ xs, int n4) {
  int i = blockIdx.x * 256 + threadIdx.x;
  if (i >= n4) return;
  float4 v = ((const float4*)x)[i];
  char4 s;
  s.x = v.x >= 0.f ? 1 : -1;
  s.y = v.y >= 0.f ? 1 : -1;
  s.z = v.z >= 0.f ? 1 : -1;
  s.w = v.w >= 0.f ? 1 : -1;
  ((char4*)xs)[i] = s;
}

// ---------------------------------------------------------------------------
// Fragment-contiguous weights (R12 layout, verified):
// wT2 bytes [f = (tap*4+icq)*16 + ocg][l = grp*16+lid][bb 0..15]
//   = sign(w[tap][ic = icq*64 + grp*16 + bb][oc = ocg*16 + lid])
__global__ __launch_bounds__(256) void k_sign_wT2(const float* __restrict__ w,
                                                  uint32_t* __restrict__ wt) {
  int u = blockIdx.x * 256 + threadIdx.x;   // 0..147455
  int f = u >> 8, r = u & 255;
  int l = r >> 2, w4 = r & 3;
  int grp = l >> 4, lid = l & 15;
  int tap = f >> 6, icq = (f >> 4) & 3, ocg = f & 15;
  int oc = ocg * 16 + lid;
  uint32_t pk = 0;
#pragma unroll
  for (int j = 0; j < 4; ++j) {
    int ic = icq * 64 + grp * 16 + w4 * 4 + j;
    float v = w[((size_t)(tap * 256 + ic)) * 256 + oc];
    pk |= (v >= 0.f ? 0x01u : 0xFFu) << (8 * j);
  }
  wt[u] = pk;
}

// ---------------------------------------------------------------------------
// Per-wave GEMM body (R12 structure + flattened 36-step loop with B-fragment
// register double-buffer one step ahead). Wave: M [(MSB)*16,(MSB+MS)*16) x
// N=128. m permuted (row=m&1, col=m>>1) so 2x2 pool = lane-local q-quad.
// A in LDS, XOR-swizzled: byte(slot s, off o) = s*256 + (o ^ ((s&7)<<4)).
template <int MODE, int MS, int MSB>
__device__ __forceinline__ void conv_body(
    const int8_t* As, const int8_t* __restrict__ wT2, int wn, int lane,
    const float* __restrict__ beta, const float* __restrict__ mean,
    const float* __restrict__ var, int8_t* __restrict__ hs,
    float* __restrict__ outp, int b, int rp)
{
  const int grp = lane >> 4, lid = lane & 15;
  const int wbase = wn * 128;
  const int cstg = grp << 4;

  int sb[MS], sb7[MS];
#pragma unroll
  for (int ms = 0; ms < MS; ++ms) {
    const int m = (MSB + ms) * 16 + lid;
    sb[ms] = (m & 1) * 58 + (m >> 1);
    sb7[ms] = sb[ms] & 7;
  }

  const int8_t* bpl = wT2 + (size_t)wn * 8192 + (size_t)lane * 16;

  v4i acc[MS][8];
#pragma unroll
  for (int i = 0; i < MS; ++i)
#pragma unroll
    for (int j = 0; j < 8; ++j) acc[i][j] = (v4i){0, 0, 0, 0};

#define LOADB(dst, st)                                                     \
  {                                                                        \
    const int8_t* p_ = bpl + (size_t)(st) * 16384;                         \
    _Pragma("unroll") for (int ns = 0; ns < 8; ++ns)                       \
        dst[ns] = *(const v4i*)(p_ + ns * 1024);                           \
  }

#define LOADA(dst, st)                                                     \
  {                                                                        \
    const int tap_ = (st) >> 2, icq_ = (st) & 3;                           \
    const int ky_ = (tap_ >= 6) ? 2 : ((tap_ >= 3) ? 1 : 0);               \
    const int kx_ = tap_ - 3 * ky_;                                        \
    const int D_ = ky_ * 58 + kx_;                                         \
    const int ko_ = cstg + icq_ * 64;                                      \
    _Pragma("unroll") for (int ms = 0; ms < MS; ++ms) {                    \
      const int s_ = sb[ms] + D_;                                          \
      dst[ms] = *(const v4i*)(As + (s_ << 8) + (ko_ ^ ((s_ & 7) << 4)));   \
    }                                                                      \
  }

#define MFMAC(af, bf)                                                      \
  __builtin_amdgcn_s_setprio(1);                                           \
  _Pragma("unroll") for (int ms = 0; ms < MS; ++ms)                        \
  _Pragma("unroll") for (int ns = 0; ns < 8; ++ns)                         \
      acc[ms][ns] = __builtin_amdgcn_mfma_i32_16x16x64_i8(                 \
          af[ms], bf[ns], acc[ms][ns], 0, 0, 0);                           \
  __builtin_amdgcn_s_setprio(0);

  v4i af[MS], bfA[8], bfB[8];
  LOADB(bfA, 0)

#pragma unroll 1
  for (int i = 0; i < 18; ++i) {
    const int s0 = 2 * i, s1 = 2 * i + 1;
    const int s2 = (s1 + 1 > 35) ? 35 : s1 + 1;
    LOADB(bfB, s1)            // prefetch next step's B (covered by MFMA below)
    LOADA(af, s0)
    MFMAC(af, bfA)
    LOADB(bfA, s2)
    LOADA(af, s1)
    MFMAC(af, bfB)
  }

#undef MFMAC
#undef LOADA
#undef LOADB

  const int rA = rp * 2;
  if (MODE == 0) {
    // BN1 + sign -> hs (standard NHWC i8)
#pragma unroll
    for (int ns = 0; ns < 8; ++ns) {
      const int oc = wbase + ns * 16 + lid;
      const float mu = mean[oc], rs = rsqrtf(var[oc] + BN_EPS), be = beta[oc];
#pragma unroll
      for (int ms = 0; ms < MS; ++ms)
#pragma unroll
        for (int q = 0; q < 4; ++q) {
          const int m = (MSB + ms) * 16 + grp * 4 + q;
          const int lr = m & 1, col = m >> 1;
          const float bnv = ((float)acc[ms][ns][q] - mu) * rs + be;
          hs[(((size_t)(b * 56 + rA + lr)) * 56 + col) * 256 + oc] =
              bnv >= 0.f ? (int8_t)1 : (int8_t)-1;
        }
    }
  } else {
    // maxpool (lane-local q-quad) + BN2 -> f32
#pragma unroll
    for (int ns = 0; ns < 8; ++ns) {
      const int oc = wbase + ns * 16 + lid;
      const float mu = mean[oc], rs = rsqrtf(var[oc] + BN_EPS), be = beta[oc];
#pragma unroll
      for (int ms = 0; ms < MS; ++ms) {
        const int mx = imax(imax(acc[ms][ns][0], acc[ms][ns][1]),
                            imax(acc[ms][ns][2], acc[ms][ns][3]));
        const int j = (MSB + ms) * 4 + grp;   // pooled col 0..27
        outp[(((size_t)(b * 28 + rp)) * 28 + j) * 256 + oc] =
            ((float)mx - mu) * rs + be;
      }
    }
  }
}

// ---------------------------------------------------------------------------
// 4 waves = 2 wm (M-halves: ms 0-3 / 4-6) x 2 wn (oc halves, N=128 each).
template <int MODE>
__global__ __launch_bounds__(256, 2) void k_conv(
    const int8_t* __restrict__ src, const int8_t* __restrict__ wT2,
    const float* __restrict__ beta, const float* __restrict__ mean,
    const float* __restrict__ var,
    int8_t* __restrict__ hs, float* __restrict__ outp)
{
  const int t = threadIdx.x;
  const int rp = blockIdx.x;          // row pair 0..27
  const int b = blockIdx.y;
  const int rr0 = rp * 2;

  __shared__ __align__(16) int8_t As[NSLOT * 256];   // 59392 B

  // Stage A once (verified R12: conflict-light, coalesced).
  for (int i = t; i < NSLOT * 16; i += 256) {
    const int s = i >> 4, c = i & 15;
    const int lr = s / 58, colst = s - lr * 58;
    const int sr = rr0 + lr - 1, sc = colst - 1;
    uint4 v;
    v.x = v.y = v.z = v.w = 0u;
    if ((unsigned)sr < 56u && (unsigned)sc < 56u)
      v = *(const uint4*)(src + (((size_t)(b * 56 + sr)) * 56 + sc) * 256 + c * 16);
    *(uint4*)(As + (s << 8) + ((c << 4) ^ ((s & 7) << 4))) = v;
  }
  __syncthreads();

  const int lane = t & 63;
  const int wv = t >> 6;
  const int wm = wv >> 1, wn = wv & 1;
  if (wm == 0)
    conv_body<MODE, 4, 0>(As, wT2, wn, lane, beta, mean, var, hs, outp, b, rp);
  else
    conv_body<MODE, 3, 4>(As, wT2, wn, lane, beta, mean, var, hs, outp, b, rp);
}

// ---------------------------------------------------------------------------
extern "C" void kernel_launch(void* const* d_in, const int* in_sizes, int n_in,
                              void* d_out, int out_size, void* d_ws, size_t ws_size,
                              hipStream_t stream) {
  const float* x     = (const float*)d_in[0];
  const float* w1    = (const float*)d_in[1];
  const float* beta1 = (const float*)d_in[2];
  const float* mean1 = (const float*)d_in[3];
  const float* var1  = (const float*)d_in[4];
  const float* w2    = (const float*)d_in[5];
  const float* beta2 = (const float*)d_in[6];
  const float* mean2 = (const float*)d_in[7];
  const float* var2  = (const float*)d_in[8];
  float* out = (float*)d_out;

  const size_t NPIX = (size_t)Bn * H * Wd * C;  // 25690112
  int8_t* xs  = (int8_t*)d_ws;
  int8_t* hs  = xs + NPIX;
  int8_t* w1t = hs + NPIX;
  int8_t* w2t = w1t + 589824;

  k_sign_x<<<dim3((int)(NPIX / 4 / 256)), 256, 0, stream>>>(x, xs, (int)(NPIX / 4));
  k_sign_wT2<<<dim3(576), 256, 0, stream>>>(w1, (uint32_t*)w1t);
  k_sign_wT2<<<dim3(576), 256, 0, stream>>>(w2, (uint32_t*)w2t);
  k_conv<0><<<dim3(28, Bn), 256, 0, stream>>>(xs, w1t, beta1, mean1, var1, hs, nullptr);
  k_conv<1><<<dim3(28, Bn), 256, 0, stream>>>(hs, w2t, beta2, mean2, var2, nullptr, out);
}

// Round 15
// 135.220 us; speedup vs baseline: 1.3869x; 1.1182x over previous
//
#include <hip/hip_runtime.h>
#include <stdint.h>

#define BN_EPS 1e-3f

constexpr int Bn = 32, H = 56, Wd = 56, C = 256;
constexpr int NSLOT = 232;          // 4 staged input rows * 58 cols (w/ halo)
typedef int v4i __attribute__((ext_vector_type(4)));

__device__ __forceinline__ int imax(int a, int b) { return a > b ? a : b; }

// ---------------------------------------------------------------------------
// sign(x) -> i8 {+1,-1}
__global__ __launch_bounds__(256) void k_sign_x(const float* __restrict__ x,
                                                int8_t* __restrict__ xs, int n4) {
  int i = blockIdx.x * 256 + threadIdx.x;
  if (i >= n4) return;
  float4 v = ((const float4*)x)[i];
  char4 s;
  s.x = v.x >= 0.f ? 1 : -1;
  s.y = v.y >= 0.f ? 1 : -1;
  s.z = v.z >= 0.f ? 1 : -1;
  s.w = v.w >= 0.f ? 1 : -1;
  ((char4*)xs)[i] = s;
}

// ---------------------------------------------------------------------------
// Fragment-contiguous weights (verified R12 layout):
// wT2 bytes [f = (tap*4+icq)*16 + ocg][l = grp*16+lid][bb 0..15]
//   = sign(w[tap][ic = icq*64 + grp*16 + bb][oc = ocg*16 + lid])
__global__ __launch_bounds__(256) void k_sign_wT2(const float* __restrict__ w,
                                                  uint32_t* __restrict__ wt) {
  int u = blockIdx.x * 256 + threadIdx.x;   // 0..147455
  int f = u >> 8, r = u & 255;
  int l = r >> 2, w4 = r & 3;
  int grp = l >> 4, lid = l & 15;
  int tap = f >> 6, icq = (f >> 4) & 3, ocg = f & 15;
  int oc = ocg * 16 + lid;
  uint32_t pk = 0;
#pragma unroll
  for (int j = 0; j < 4; ++j) {
    int ic = icq * 64 + grp * 16 + w4 * 4 + j;
    float v = w[((size_t)(tap * 256 + ic)) * 256 + oc];
    pk |= (v >= 0.f ? 0x01u : 0xFFu) << (8 * j);
  }
  wt[u] = pk;
}

// ---------------------------------------------------------------------------
// Per-wave GEMM body. NEW partition: wave = ALL 7 m-subtiles x 4 n-subtiles
// (N=64 slice) -> zero B redundancy within the block (B L1 traffic halves vs
// R12/R14's 2wm x 2wn). acc[7][4] = 112 VGPR. m permuted (row=m&1, col=m>>1)
// so 2x2 pool = lane-local q-quad. A in LDS, XOR-swizzled:
// byte(slot s, off o) = s*256 + (o ^ ((s&7)<<4)).
template <int MODE>
__device__ __forceinline__ void conv_body(
    const int8_t* As, const int8_t* __restrict__ wT2, int wn, int lane,
    const float* __restrict__ beta, const float* __restrict__ mean,
    const float* __restrict__ var, int8_t* __restrict__ hs,
    float* __restrict__ outp, int b, int rp)
{
  const int grp = lane >> 4, lid = lane & 15;
  const int wbase = wn * 64;
  const int cstg = grp << 4;

  int sb[7];
#pragma unroll
  for (int ms = 0; ms < 7; ++ms) {
    const int m = ms * 16 + lid;
    sb[ms] = (m & 1) * 58 + (m >> 1);
  }

  // wave's B slice: ocg in [wn*4, wn*4+4) -> contiguous 4KB per step-frag set
  const int8_t* bpl = wT2 + (size_t)wn * 4096 + (size_t)lane * 16;

  v4i acc[7][4];
#pragma unroll
  for (int i = 0; i < 7; ++i)
#pragma unroll
    for (int j = 0; j < 4; ++j) acc[i][j] = (v4i){0, 0, 0, 0};

#define LOADB(dst, st)                                                     \
  {                                                                        \
    const int8_t* p_ = bpl + (size_t)(st) * 16384;                         \
    _Pragma("unroll") for (int ns = 0; ns < 4; ++ns)                       \
        dst[ns] = *(const v4i*)(p_ + ns * 1024);                           \
  }

#define LOADA(dst, st)                                                     \
  {                                                                        \
    const int tap_ = (st) >> 2, icq_ = (st) & 3;                           \
    const int ky_ = (tap_ >= 6) ? 2 : ((tap_ >= 3) ? 1 : 0);               \
    const int kx_ = tap_ - 3 * ky_;                                        \
    const int D_ = ky_ * 58 + kx_;                                         \
    const int ko_ = cstg + icq_ * 64;                                      \
    _Pragma("unroll") for (int ms = 0; ms < 7; ++ms) {                     \
      const int s_ = sb[ms] + D_;                                          \
      dst[ms] = *(const v4i*)(As + (s_ << 8) + (ko_ ^ ((s_ & 7) << 4)));   \
    }                                                                      \
  }

#define MFMAC(af, bf)                                                      \
  __builtin_amdgcn_s_setprio(1);                                           \
  _Pragma("unroll") for (int ms = 0; ms < 7; ++ms)                         \
  _Pragma("unroll") for (int ns = 0; ns < 4; ++ns)                         \
      acc[ms][ns] = __builtin_amdgcn_mfma_i32_16x16x64_i8(                 \
          af[ms], bf[ns], acc[ms][ns], 0, 0, 0);                           \
  __builtin_amdgcn_s_setprio(0);

  v4i af[7], bfA[4], bfB[4];
  LOADB(bfA, 0)

#pragma unroll 1
  for (int i = 0; i < 18; ++i) {
    const int s0 = 2 * i, s1 = 2 * i + 1;
    const int s2 = (s1 + 1 > 35) ? 35 : s1 + 1;
    LOADB(bfB, s1)            // prefetch next step's B under this MFMA cluster
    LOADA(af, s0)
    MFMAC(af, bfA)
    LOADB(bfA, s2)
    LOADA(af, s1)
    MFMAC(af, bfB)
  }

#undef MFMAC
#undef LOADA
#undef LOADB

  const int rA = rp * 2;
  if (MODE == 0) {
    // BN1 + sign -> hs (standard NHWC i8)
#pragma unroll
    for (int ns = 0; ns < 4; ++ns) {
      const int oc = wbase + ns * 16 + lid;
      const float mu = mean[oc], rs = rsqrtf(var[oc] + BN_EPS), be = beta[oc];
#pragma unroll
      for (int ms = 0; ms < 7; ++ms)
#pragma unroll
        for (int q = 0; q < 4; ++q) {
          const int m = ms * 16 + grp * 4 + q;
          const int lr = m & 1, col = m >> 1;
          const float bnv = ((float)acc[ms][ns][q] - mu) * rs + be;
          hs[(((size_t)(b * 56 + rA + lr)) * 56 + col) * 256 + oc] =
              bnv >= 0.f ? (int8_t)1 : (int8_t)-1;
        }
    }
  } else {
    // maxpool (lane-local q-quad) + BN2 -> f32
#pragma unroll
    for (int ns = 0; ns < 4; ++ns) {
      const int oc = wbase + ns * 16 + lid;
      const float mu = mean[oc], rs = rsqrtf(var[oc] + BN_EPS), be = beta[oc];
#pragma unroll
      for (int ms = 0; ms < 7; ++ms) {
        const int mx = imax(imax(acc[ms][ns][0], acc[ms][ns][1]),
                            imax(acc[ms][ns][2], acc[ms][ns][3]));
        const int j = ms * 4 + grp;   // pooled col 0..27
        outp[(((size_t)(b * 28 + rp)) * 28 + j) * 256 + oc] =
            ((float)mx - mu) * rs + be;
      }
    }
  }
}

// ---------------------------------------------------------------------------
// 4 waves, each = N=64 slice (wn = wave id) x all of M=112.
template <int MODE>
__global__ __launch_bounds__(256, 2) void k_conv(
    const int8_t* __restrict__ src, const int8_t* __restrict__ wT2,
    const float* __restrict__ beta, const float* __restrict__ mean,
    const float* __restrict__ var,
    int8_t* __restrict__ hs, float* __restrict__ outp)
{
  const int t = threadIdx.x;
  const int rp = blockIdx.x;          // row pair 0..27
  const int b = blockIdx.y;
  const int rr0 = rp * 2;

  __shared__ __align__(16) int8_t As[NSLOT * 256];   // 59392 B

  // Stage A once (verified R12: conflict-light, coalesced).
  for (int i = t; i < NSLOT * 16; i += 256) {
    const int s = i >> 4, c = i & 15;
    const int lr = s / 58, colst = s - lr * 58;
    const int sr = rr0 + lr - 1, sc = colst - 1;
    uint4 v;
    v.x = v.y = v.z = v.w = 0u;
    if ((unsigned)sr < 56u && (unsigned)sc < 56u)
      v = *(const uint4*)(src + (((size_t)(b * 56 + sr)) * 56 + sc) * 256 + c * 16);
    *(uint4*)(As + (s << 8) + ((c << 4) ^ ((s & 7) << 4))) = v;
  }
  __syncthreads();

  const int lane = t & 63;
  const int wn = t >> 6;              // 0..3
  conv_body<MODE>(As, wT2, wn, lane, beta, mean, var, hs, outp, b, rp);
}

// ---------------------------------------------------------------------------
extern "C" void kernel_launch(void* const* d_in, const int* in_sizes, int n_in,
                              void* d_out, int out_size, void* d_ws, size_t ws_size,
                              hipStream_t stream) {
  const float* x     = (const float*)d_in[0];
  const float* w1    = (const float*)d_in[1];
  const float* beta1 = (const float*)d_in[2];
  const float* mean1 = (const float*)d_in[3];
  const float* var1  = (const float*)d_in[4];
  const float* w2    = (const float*)d_in[5];
  const float* beta2 = (const float*)d_in[6];
  const float* mean2 = (const float*)d_in[7];
  const float* var2  = (const float*)d_in[8];
  float* out = (float*)d_out;

  const size_t NPIX = (size_t)Bn * H * Wd * C;  // 25690112
  int8_t* xs  = (int8_t*)d_ws;
  int8_t* hs  = xs + NPIX;
  int8_t* w1t = hs + NPIX;
  int8_t* w2t = w1t + 589824;

  k_sign_x<<<dim3((int)(NPIX / 4 / 256)), 256, 0, stream>>>(x, xs, (int)(NPIX / 4));
  k_sign_wT2<<<dim3(576), 256, 0, stream>>>(w1, (uint32_t*)w1t);
  k_sign_wT2<<<dim3(576), 256, 0, stream>>>(w2, (uint32_t*)w2t);
  k_conv<0><<<dim3(28, Bn), 256, 0, stream>>>(xs, w1t, beta1, mean1, var1, hs, nullptr);
  k_conv<1><<<dim3(28, Bn), 256, 0, stream>>>(hs, w2t, beta2, mean2, var2, nullptr, out);
}